// Round 3
// baseline (637.146 us; speedup 1.0000x reference)
//
#include <hip/hip_runtime.h>
#include <hip/hip_bf16.h>

#define T_DIM 8192
#define H_DIM 2048
#define F_DIM 5632

typedef __attribute__((ext_vector_type(4))) float f32x4;
typedef __attribute__((ext_vector_type(8))) short bf16x8;

static __device__ __forceinline__ void gload16(const void* g, void* l) {
    __builtin_amdgcn_global_load_lds(
        (const __attribute__((address_space(1))) void*)g,
        (__attribute__((address_space(3))) void*)l,
        16, 0, 0);
}

static __device__ __forceinline__ unsigned short f2bf(float f) {
    unsigned int u = __float_as_uint(f);
    u += 0x7fffu + ((u >> 16) & 1u);
    return (unsigned short)(u >> 16);
}

static __device__ __forceinline__ float bf2f(unsigned short u) {
    return __uint_as_float(((unsigned int)u) << 16);
}

// ---- f32 -> bf16 conversion (optionally expert-sliced) ----
__global__ __launch_bounds__(256)
void cvt_f32_bf16(const float* __restrict__ base, const int* __restrict__ eidx,
                  long per_expert, unsigned short* __restrict__ dst, long n)
{
    const float* src = base;
    if (eidx) src += (long)(*eidx) * per_expert;
    const long stride = (long)gridDim.x * blockDim.x;
    for (long i = (long)blockIdx.x * blockDim.x + threadIdx.x; i * 4 < n; i += stride) {
        const float4 v = *(const float4*)(src + i * 4);
        ushort4 o;
        o.x = f2bf(v.x); o.y = f2bf(v.y); o.z = f2bf(v.z); o.w = f2bf(v.w);
        *(ushort4*)(dst + i * 4) = o;
    }
}

// ---- helpers for the 256x256 / BK=64 8-wave pipelined GEMM ----
// Staging: half (128 rows) of a 256x64 bf16 tile. LDS dest lane-linear;
// global source column inverse-XOR-swizzled (rule #21).
static __device__ __forceinline__ void stage_half(const unsigned short* __restrict__ g,
                                                  long grow0, long ldk, long kb,
                                                  unsigned short* l, int t, int i0)
{
    const int r  = t >> 3;
    const int cc = ((t & 7) ^ (r & 7)) << 3;   // swizzled source column (elems)
    #pragma unroll
    for (int i = i0; i < i0 + 2; ++i)
        gload16(g + (grow0 + i * 64 + r) * ldk + kb + cc,
                l + i * 4096 + t * 8);
}

// Swizzled fragment read: logical 8-elem chunk (kk*4+q) -> physical ^(row&7).
static __device__ __forceinline__ bf16x8 ldsfrag(const unsigned short* base,
                                                 int row, int kk, int q)
{
    return *(const bf16x8*)(base + row * 64 + (((kk * 4 + q) ^ (row & 7)) << 3));
}

#define PHASE_BODY(p, STAGE_STMT)                                              \
    {                                                                          \
        bf16x8 af[2][2];                                                       \
        _Pragma("unroll")                                                      \
        for (int l_ = 0; l_ < 2; ++l_)                                         \
            _Pragma("unroll")                                                  \
            for (int kk = 0; kk < 2; ++kk)                                     \
                af[l_][kk] = ldsfrag(la, wm * 128 + (p) * 32 + l_ * 16 + lr, kk, q); \
        STAGE_STMT;                                                            \
        __builtin_amdgcn_s_barrier();                                          \
        __builtin_amdgcn_s_setprio(1);                                         \
        _Pragma("unroll")                                                      \
        for (int l_ = 0; l_ < 2; ++l_)                                         \
            _Pragma("unroll")                                                  \
            for (int ni = 0; ni < 4; ++ni)                                     \
                _Pragma("unroll")                                              \
                for (int kk = 0; kk < 2; ++kk)                                 \
                    acc[(p) * 2 + l_][ni] = __builtin_amdgcn_mfma_f32_16x16x32_bf16( \
                        af[l_][kk], bf[ni][kk], acc[(p) * 2 + l_][ni], 0, 0, 0);     \
        __builtin_amdgcn_s_setprio(0);                                         \
        __builtin_amdgcn_s_barrier();                                          \
    }

// ---- Unified 256x256 GEMM: C = A[M,K] * B[N,K]^T ----
// MODE 0: store f32.  MODE 1: store raw bf16 (gate).
// MODE 2: load gate bf16 from `gate`, h = silu(g)*acc, store bf16 (in place ok).
template<int MODE, int KDIM, int NBN>
__global__ __launch_bounds__(512, 2)
void gemm256(const unsigned short* __restrict__ A,
             const unsigned short* __restrict__ B,
             void* outp, const unsigned short* gate)
{
    constexpr int  NK   = KDIM / 64;
    constexpr long NTOT = (long)NBN * 256;

    __shared__ __align__(16) unsigned short sAll[4 * 16384];  // 128 KiB

    const int tid  = threadIdx.x;
    const int lane = tid & 63;
    const int wid  = tid >> 6;
    const int wm   = wid >> 2;
    const int wn   = wid & 3;
    const int q    = lane >> 4;
    const int lr   = lane & 15;

    const int nwg = gridDim.x;                     // multiple of 8
    const int bid = blockIdx.x;
    const int cpx = nwg >> 3;
    const int swz = (bid & 7) * cpx + (bid >> 3);
    const int bm  = swz / NBN;
    const int bn  = swz % NBN;

    const long arow0 = (long)bm * 256;
    const long brow0 = (long)bn * 256;

    f32x4 acc[8][4] = {};

    // prologue: A(0),B(0) -> buf0 ; B(1) -> buf1   (A(1) issued at TOP(0))
    stage_half(A, arow0, KDIM, 0,  sAll,          tid, 0);
    stage_half(A, arow0, KDIM, 0,  sAll,          tid, 2);
    stage_half(B, brow0, KDIM, 0,  sAll + 16384,  tid, 0);
    stage_half(B, brow0, KDIM, 0,  sAll + 16384,  tid, 2);
    stage_half(B, brow0, KDIM, 64, sAll + 49152,  tid, 0);
    stage_half(B, brow0, KDIM, 64, sAll + 49152,  tid, 2);

    for (int j = 0; j < NK; ++j) {
        unsigned short* la = sAll + (j & 1) * 32768;
        unsigned short* lb = la + 16384;

        if (j + 1 < NK) {
            unsigned short* na = sAll + ((j + 1) & 1) * 32768;
            stage_half(A, arow0, KDIM, (long)(j + 1) * 64, na, tid, 0);
            stage_half(A, arow0, KDIM, (long)(j + 1) * 64, na, tid, 2);
            asm volatile("s_waitcnt vmcnt(8)" ::: "memory");  // drains tile j
        } else {
            asm volatile("s_waitcnt vmcnt(0)" ::: "memory");
        }
        __builtin_amdgcn_s_barrier();

        // phase 0 hoists all B-frags; B region then dead -> stage B(j+2) into it
        bf16x8 bf[4][2];
        #pragma unroll
        for (int ni = 0; ni < 4; ++ni)
            #pragma unroll
            for (int kk = 0; kk < 2; ++kk)
                bf[ni][kk] = ldsfrag(lb, wn * 64 + ni * 16 + lr, kk, q);

        PHASE_BODY(0, {})
        PHASE_BODY(1, { if (j + 2 < NK) stage_half(B, brow0, KDIM, (long)(j + 2) * 64, lb, tid, 0); })
        PHASE_BODY(2, { if (j + 2 < NK) stage_half(B, brow0, KDIM, (long)(j + 2) * 64, lb, tid, 2); })
        PHASE_BODY(3, {})
    }

    // epilogue (per-wave independent; all VMEM drained)
    const long orow = (long)bm * 256 + wm * 128;
    const long ocol = (long)bn * 256 + wn * 64;
    #pragma unroll
    for (int mi = 0; mi < 8; ++mi)
        #pragma unroll
        for (int ni = 0; ni < 4; ++ni)
            #pragma unroll
            for (int r = 0; r < 4; ++r) {
                const long idx = (orow + mi * 16 + q * 4 + r) * NTOT + (ocol + ni * 16 + lr);
                if constexpr (MODE == 0) {
                    ((float*)outp)[idx] = acc[mi][ni][r];
                } else if constexpr (MODE == 1) {
                    ((unsigned short*)outp)[idx] = f2bf(acc[mi][ni][r]);
                } else {
                    const float g = bf2f(gate[idx]);
                    const float h = __fdividef(g, 1.0f + __expf(-g)) * acc[mi][ni][r];
                    ((unsigned short*)outp)[idx] = f2bf(h);
                }
            }
}

extern "C" void kernel_launch(void* const* d_in, const int* in_sizes, int n_in,
                              void* d_out, int out_size, void* d_ws, size_t ws_size,
                              hipStream_t stream)
{
    const int*   eidx = (const int*)d_in[0];
    const float* x    = (const float*)d_in[1];
    const float* w1   = (const float*)d_in[2];
    const float* w2   = (const float*)d_in[3];
    const float* w3   = (const float*)d_in[4];
    float* out = (float*)d_out;

    unsigned short* Xb  = (unsigned short*)d_ws;
    unsigned short* W1b = Xb  + (long)T_DIM * H_DIM;
    unsigned short* W2b = W1b + (long)F_DIM * H_DIM;
    unsigned short* W3b = W2b + (long)F_DIM * H_DIM;
    unsigned short* Hb  = W3b + (long)H_DIM * F_DIM;   // gate then H, in place

    cvt_f32_bf16<<<2048, 256, 0, stream>>>(x,  nullptr, 0, Xb, (long)T_DIM * H_DIM);
    cvt_f32_bf16<<<2048, 256, 0, stream>>>(w1, eidx, (long)F_DIM * H_DIM, W1b, (long)F_DIM * H_DIM);
    cvt_f32_bf16<<<2048, 256, 0, stream>>>(w2, eidx, (long)F_DIM * H_DIM, W2b, (long)F_DIM * H_DIM);
    cvt_f32_bf16<<<2048, 256, 0, stream>>>(w3, eidx, (long)H_DIM * F_DIM, W3b, (long)H_DIM * F_DIM);

    // gate = X*W1^T (raw bf16 into Hb)
    gemm256<1, H_DIM, F_DIM / 256><<<(T_DIM / 256) * (F_DIM / 256), 512, 0, stream>>>(
        Xb, W1b, Hb, nullptr);
    // up = X*W2^T; H = silu(gate)*up, overwriting Hb tile-in-place
    gemm256<2, H_DIM, F_DIM / 256><<<(T_DIM / 256) * (F_DIM / 256), 512, 0, stream>>>(
        Xb, W2b, Hb, Hb);
    // out = H*W3^T (f32)
    gemm256<0, F_DIM, H_DIM / 256><<<(T_DIM / 256) * (H_DIM / 256), 512, 0, stream>>>(
        Hb, W3b, out, nullptr);
}

// Round 4
// 599.392 us; speedup vs baseline: 1.0630x; 1.0630x over previous
//
#include <hip/hip_runtime.h>
#include <hip/hip_bf16.h>

#define T_DIM 8192
#define H_DIM 2048
#define F_DIM 5632

typedef __attribute__((ext_vector_type(4))) float f32x4;
typedef __attribute__((ext_vector_type(8))) short bf16x8;

static __device__ __forceinline__ void gload16(const void* g, void* l) {
    __builtin_amdgcn_global_load_lds(
        (const __attribute__((address_space(1))) void*)g,
        (__attribute__((address_space(3))) void*)l,
        16, 0, 0);
}

static __device__ __forceinline__ unsigned short f2bf(float f) {
    unsigned int u = __float_as_uint(f);
    u += 0x7fffu + ((u >> 16) & 1u);
    return (unsigned short)(u >> 16);
}

static __device__ __forceinline__ float bf2f(unsigned short u) {
    return __uint_as_float(((unsigned int)u) << 16);
}

// ---- f32 -> bf16 conversion: X ----
__global__ __launch_bounds__(256)
void cvt_x(const float* __restrict__ src, unsigned short* __restrict__ dst, long n)
{
    const long stride = (long)gridDim.x * blockDim.x;
    for (long i = (long)blockIdx.x * blockDim.x + threadIdx.x; i * 4 < n; i += stride) {
        const float4 v = *(const float4*)(src + i * 4);
        ushort4 o;
        o.x = f2bf(v.x); o.y = f2bf(v.y); o.z = f2bf(v.z); o.w = f2bf(v.w);
        *(ushort4*)(dst + i * 4) = o;
    }
}

// ---- f32 -> bf16 conversion: the three expert weight slices (equal size) ----
__global__ __launch_bounds__(256)
void cvt_w(const float* __restrict__ w1, const float* __restrict__ w2,
           const float* __restrict__ w3, const int* __restrict__ eidx,
           unsigned short* __restrict__ W1b, unsigned short* __restrict__ W2b,
           unsigned short* __restrict__ W3b)
{
    const long seg = (long)F_DIM * H_DIM;     // == H_DIM*F_DIM
    const long e   = (long)(*eidx);
    const long nchunks = 3 * seg / 4;
    const long stride = (long)gridDim.x * blockDim.x;
    for (long i = (long)blockIdx.x * blockDim.x + threadIdx.x; i < nchunks; i += stride) {
        const long t = i * 4;
        const int  s = (int)(t / seg);
        const long o = t - (long)s * seg;
        const float* src = (s == 0 ? w1 : s == 1 ? w2 : w3) + e * seg + o;
        unsigned short* dst = (s == 0 ? W1b : s == 1 ? W2b : W3b) + o;
        const float4 v = *(const float4*)src;
        ushort4 ov;
        ov.x = f2bf(v.x); ov.y = f2bf(v.y); ov.z = f2bf(v.z); ov.w = f2bf(v.w);
        *(ushort4*)dst = ov;
    }
}

// ---- helpers for the 256x256 / BK=64 8-wave pipelined GEMM ----
static __device__ __forceinline__ void stage_half(const unsigned short* __restrict__ g,
                                                  long grow0, long ldk, long kb,
                                                  unsigned short* l, int t, int i0)
{
    const int r  = t >> 3;
    const int cc = ((t & 7) ^ (r & 7)) << 3;   // inverse-swizzled source column
    #pragma unroll
    for (int i = i0; i < i0 + 2; ++i)
        gload16(g + (grow0 + i * 64 + r) * ldk + kb + cc,
                l + i * 4096 + t * 8);
}

static __device__ __forceinline__ bf16x8 ldsfrag(const unsigned short* base,
                                                 int row, int kk, int q)
{
    return *(const bf16x8*)(base + row * 64 + (((kk * 4 + q) ^ (row & 7)) << 3));
}

#define PHASE_BODY(p, STAGE_STMT)                                              \
    {                                                                          \
        bf16x8 af[2][2];                                                       \
        _Pragma("unroll")                                                      \
        for (int l_ = 0; l_ < 2; ++l_)                                         \
            _Pragma("unroll")                                                  \
            for (int kk = 0; kk < 2; ++kk)                                     \
                af[l_][kk] = ldsfrag(la, wm * 128 + (p) * 32 + l_ * 16 + lr, kk, q); \
        STAGE_STMT;                                                            \
        __builtin_amdgcn_s_barrier();                                          \
        __builtin_amdgcn_s_setprio(1);                                         \
        _Pragma("unroll")                                                      \
        for (int l_ = 0; l_ < 2; ++l_)                                         \
            _Pragma("unroll")                                                  \
            for (int ni = 0; ni < 4; ++ni)                                     \
                _Pragma("unroll")                                              \
                for (int kk = 0; kk < 2; ++kk)                                 \
                    acc[(p) * 2 + l_][ni] = __builtin_amdgcn_mfma_f32_16x16x32_bf16( \
                        af[l_][kk], bf[ni][kk], acc[(p) * 2 + l_][ni], 0, 0, 0);     \
        __builtin_amdgcn_s_setprio(0);                                         \
        __builtin_amdgcn_s_barrier();                                          \
    }

// ---- Unified 256x256 GEMM: C = A[M,K] * B[N,K]^T ----
// MODE 0: store f32 row-major.
// MODE 1: store bf16 row-major (gate, fallback path).
// MODE 2: read gate bf16 row-major, h=silu(g)*acc, store bf16 (fallback).
// MODE 3: store gate bf16 BLOCKED (chunk-major, thread-coalesced).
// MODE 4: prefetch gate BLOCKED into regs in last K-iter, h=silu(g)*acc,
//         store bf16 row-major.
template<int MODE, int KDIM, int NBN>
__global__ __launch_bounds__(512, 2)
void gemm256(const unsigned short* __restrict__ A,
             const unsigned short* __restrict__ B,
             void* outp, unsigned short* gate)
{
    constexpr int  NK   = KDIM / 64;
    constexpr long NTOT = (long)NBN * 256;

    __shared__ __align__(16) unsigned short sAll[4 * 16384];  // 128 KiB

    const int tid  = threadIdx.x;
    const int lane = tid & 63;
    const int wid  = tid >> 6;
    const int wm   = wid >> 2;
    const int wn   = wid & 3;
    const int q    = lane >> 4;
    const int lr   = lane & 15;

    const int nwg = gridDim.x;                     // multiple of 8
    const int bid = blockIdx.x;
    const int cpx = nwg >> 3;
    const int swz = (bid & 7) * cpx + (bid >> 3);
    const int bm  = swz / NBN;
    const int bn  = swz % NBN;

    const long arow0 = (long)bm * 256;
    const long brow0 = (long)bn * 256;
    const long tileBase = ((long)bm * NBN + bn) * 65536L;   // 256*256 elems

    f32x4 acc[8][4] = {};

    // prologue: A(0),B(0) -> buf0 ; B(1) -> buf1
    stage_half(A, arow0, KDIM, 0,  sAll,          tid, 0);
    stage_half(A, arow0, KDIM, 0,  sAll,          tid, 2);
    stage_half(B, brow0, KDIM, 0,  sAll + 16384,  tid, 0);
    stage_half(B, brow0, KDIM, 0,  sAll + 16384,  tid, 2);
    stage_half(B, brow0, KDIM, 64, sAll + 49152,  tid, 0);
    stage_half(B, brow0, KDIM, 64, sAll + 49152,  tid, 2);

    for (int j = 0; j < NK - 1; ++j) {
        unsigned short* la = sAll + (j & 1) * 32768;
        unsigned short* lb = la + 16384;
        unsigned short* na = sAll + ((j + 1) & 1) * 32768;
        stage_half(A, arow0, KDIM, (long)(j + 1) * 64, na, tid, 0);
        stage_half(A, arow0, KDIM, (long)(j + 1) * 64, na, tid, 2);
        asm volatile("s_waitcnt vmcnt(8)" ::: "memory");  // drains tile j
        __builtin_amdgcn_s_barrier();

        bf16x8 bf[4][2];
        #pragma unroll
        for (int ni = 0; ni < 4; ++ni)
            #pragma unroll
            for (int kk = 0; kk < 2; ++kk)
                bf[ni][kk] = ldsfrag(lb, wn * 64 + ni * 16 + lr, kk, q);

        PHASE_BODY(0, {})
        PHASE_BODY(1, { if (j + 2 < NK) stage_half(B, brow0, KDIM, (long)(j + 2) * 64, lb, tid, 0); })
        PHASE_BODY(2, { if (j + 2 < NK) stage_half(B, brow0, KDIM, (long)(j + 2) * 64, lb, tid, 2); })
        PHASE_BODY(3, {})
    }

    // peeled last iteration (j = NK-1): drain, optional gate prefetch
    ushort4 pre[32];
    {
        const int j = NK - 1;
        unsigned short* la = sAll + (j & 1) * 32768;
        unsigned short* lb = la + 16384;
        asm volatile("s_waitcnt vmcnt(0)" ::: "memory");
        __builtin_amdgcn_s_barrier();

        if constexpr (MODE == 4) {
            #pragma unroll
            for (int mi = 0; mi < 8; ++mi)
                #pragma unroll
                for (int ni = 0; ni < 4; ++ni)
                    pre[mi * 4 + ni] = *(const ushort4*)(
                        gate + tileBase + (long)(mi * 4 + ni) * 2048 + (long)tid * 4);
        }

        bf16x8 bf[4][2];
        #pragma unroll
        for (int ni = 0; ni < 4; ++ni)
            #pragma unroll
            for (int kk = 0; kk < 2; ++kk)
                bf[ni][kk] = ldsfrag(lb, wn * 64 + ni * 16 + lr, kk, q);

        PHASE_BODY(0, {})
        PHASE_BODY(1, {})
        PHASE_BODY(2, {})
        PHASE_BODY(3, {})
    }

    // epilogue
    if constexpr (MODE == 3) {
        #pragma unroll
        for (int mi = 0; mi < 8; ++mi)
            #pragma unroll
            for (int ni = 0; ni < 4; ++ni) {
                ushort4 o;
                o.x = f2bf(acc[mi][ni][0]); o.y = f2bf(acc[mi][ni][1]);
                o.z = f2bf(acc[mi][ni][2]); o.w = f2bf(acc[mi][ni][3]);
                *(ushort4*)(gate + tileBase + (long)(mi * 4 + ni) * 2048 + (long)tid * 4) = o;
            }
    } else {
        const long orow = (long)bm * 256 + wm * 128;
        const long ocol = (long)bn * 256 + wn * 64;
        #pragma unroll
        for (int mi = 0; mi < 8; ++mi)
            #pragma unroll
            for (int ni = 0; ni < 4; ++ni)
                #pragma unroll
                for (int r = 0; r < 4; ++r) {
                    const long idx = (orow + mi * 16 + q * 4 + r) * NTOT + (ocol + ni * 16 + lr);
                    if constexpr (MODE == 0) {
                        ((float*)outp)[idx] = acc[mi][ni][r];
                    } else if constexpr (MODE == 1) {
                        ((unsigned short*)outp)[idx] = f2bf(acc[mi][ni][r]);
                    } else if constexpr (MODE == 2) {
                        const float g = bf2f(gate[idx]);
                        const float h = __fdividef(g, 1.0f + __expf(-g)) * acc[mi][ni][r];
                        ((unsigned short*)outp)[idx] = f2bf(h);
                    } else {  // MODE == 4
                        const float g = bf2f((&pre[mi * 4 + ni].x)[r]);
                        const float h = __fdividef(g, 1.0f + __expf(-g)) * acc[mi][ni][r];
                        ((unsigned short*)outp)[idx] = f2bf(h);
                    }
                }
    }
}

extern "C" void kernel_launch(void* const* d_in, const int* in_sizes, int n_in,
                              void* d_out, int out_size, void* d_ws, size_t ws_size,
                              hipStream_t stream)
{
    const int*   eidx = (const int*)d_in[0];
    const float* x    = (const float*)d_in[1];
    const float* w1   = (const float*)d_in[2];
    const float* w2   = (const float*)d_in[3];
    const float* w3   = (const float*)d_in[4];
    float* out = (float*)d_out;

    const size_t SZ_X = (size_t)T_DIM * H_DIM;   // elems
    const size_t SZ_W = (size_t)F_DIM * H_DIM;
    const size_t SZ_H = (size_t)T_DIM * F_DIM;

    unsigned short* Xb  = (unsigned short*)d_ws;
    unsigned short* W1b = Xb  + SZ_X;
    unsigned short* W2b = W1b + SZ_W;
    unsigned short* W3b = W2b + SZ_W;
    unsigned short* Hb  = W3b + SZ_W;
    unsigned short* Gb  = Hb  + SZ_H;            // blocked gate (extra 92 MB)

    const size_t need_blocked = (SZ_X + 3 * SZ_W + 2 * SZ_H) * 2;

    cvt_x<<<2048, 256, 0, stream>>>(x, Xb, (long)SZ_X);
    cvt_w<<<2048, 256, 0, stream>>>(w1, w2, w3, eidx, W1b, W2b, W3b);

    constexpr int NBN1 = F_DIM / 256;   // 22
    constexpr int NBN2 = H_DIM / 256;   // 8
    const int grid1 = (T_DIM / 256) * NBN1;   // 704
    const int grid2 = (T_DIM / 256) * NBN2;   // 256

    if (ws_size >= need_blocked) {
        // gate = X*W1^T -> blocked Gb
        gemm256<3, H_DIM, NBN1><<<grid1, 512, 0, stream>>>(Xb, W1b, nullptr, Gb);
        // up = X*W2^T; H = silu(gate)*up -> row-major Hb (gate prefetched in regs)
        gemm256<4, H_DIM, NBN1><<<grid1, 512, 0, stream>>>(Xb, W2b, Hb, Gb);
    } else {
        // fallback (round-3 path): row-major gate in Hb, combined in place
        gemm256<1, H_DIM, NBN1><<<grid1, 512, 0, stream>>>(Xb, W1b, Hb, nullptr);
        gemm256<2, H_DIM, NBN1><<<grid1, 512, 0, stream>>>(Xb, W2b, Hb, Hb);
    }
    // out = H*W3^T (f32)
    gemm256<0, F_DIM, NBN2><<<grid2, 512, 0, stream>>>(Hb, W3b, out, nullptr);
}